// Round 1
// baseline (112.597 us; speedup 1.0000x reference)
//
#include <hip/hip_runtime.h>
#include <hip/hip_bf16.h>

// Problem constants
constexpr int BATCH = 4096;
constexpr int IN    = 512;
constexpr int OUT   = 512;
constexpr int ORD   = 8;
constexpr int NK    = ORD + 1;        // 9
constexpr int KK    = IN * NK;        // 4608  (GEMM inner dim)
constexpr float FA  = 1.0f, FB = 1.0f;

constexpr int SPLITK = 4;
constexpr int KTILES_PER_SPLIT = KK / (32 * SPLITK); // 36

typedef __attribute__((ext_vector_type(8))) short short8;   // 8 bf16 = 4 VGPRs
typedef __attribute__((ext_vector_type(4))) float floatx4;  // MFMA C/D

#define AS1 __attribute__((address_space(1)))
#define AS3 __attribute__((address_space(3)))

__device__ __forceinline__ void gload_lds16(const void* g, void* l) {
    // async global->LDS, 16B per lane; LDS dest = wave-uniform base + lane*16
    __builtin_amdgcn_global_load_lds((const AS1 unsigned int*)g,
                                     (AS3 unsigned int*)l, 16, 0, 0);
}

// ---------------------------------------------------------------------------
// Kernel 1: A[b, k*512 + i] = bf16( J_k(tanh(x[b,i])) )
// ---------------------------------------------------------------------------
__global__ __launch_bounds__(256) void jprep(const float* __restrict__ x,
                                             __hip_bfloat16* __restrict__ J) {
    int idx = blockIdx.x * 256 + threadIdx.x;      // [0, 4096*512)
    float t = tanhf(x[idx]);
    int b = idx >> 9, i = idx & 511;
    __hip_bfloat16* row = J + (size_t)b * KK + i;  // stride 512 per k -> coalesced stores
    float p0 = 1.0f;
    float p1 = 0.5f * (FA + FB + 2.0f) * t - 0.5f * (FA - FB);
    row[0]   = __float2bfloat16(p0);
    row[512] = __float2bfloat16(p1);
#pragma unroll
    for (int n = 2; n <= ORD; ++n) {
        float fn = (float)n;
        float k1 = (2.f*fn+FA+FB)*(2.f*fn+FA+FB-1.f) / (2.f*fn*(fn+FA+FB));
        float k2 = (2.f*fn+FA+FB-1.f)*(FA*FA-FB*FB) /
                   (2.f*fn*(fn+FA+FB)*(2.f*fn+FA+FB-2.f));
        float k3 = (fn+FA-1.f)*(fn+FB-1.f)*(2.f*fn+FA+FB) /
                   (fn*(fn+FA+FB)*(2.f*fn+FA+FB-2.f));
        float p2 = (k1*t + k2)*p1 - k3*p0;
        row[n * 512] = __float2bfloat16(p2);
        p0 = p1; p1 = p2;
    }
}

// ---------------------------------------------------------------------------
// Kernel 2: Cb[o, k*512 + i] = bf16( coeff[o,i,k] * w[o,i] )
// ---------------------------------------------------------------------------
__global__ __launch_bounds__(256) void cprep(const float* __restrict__ w,
                                             const float* __restrict__ coeff,
                                             __hip_bfloat16* __restrict__ C) {
    int idx = blockIdx.x * 256 + threadIdx.x;      // [0, 512*512)
    float wv = w[idx];
    const float* cf = coeff + (size_t)idx * NK;
    int o = idx >> 9, i = idx & 511;
    __hip_bfloat16* row = C + (size_t)o * KK + i;
#pragma unroll
    for (int k = 0; k < NK; ++k)
        row[k * 512] = __float2bfloat16(cf[k] * wv);
}

// ---------------------------------------------------------------------------
// Kernel 3: split-K GEMM  P[z][m][n] = sum_{k in chunk z} A[m,k]*B[n,k]
// 128x128x32 tile, 256 threads (2x2 waves, 64x64 per wave, 4x4 MFMA frags)
// ---------------------------------------------------------------------------
__global__ __launch_bounds__(256, 2) void gemm_splitk(
        const __hip_bfloat16* __restrict__ A,   // [4096][4608]
        const __hip_bfloat16* __restrict__ B,   // [512][4608]
        float* __restrict__ P)                  // [SPLITK][4096][512]
{
    __shared__ __hip_bfloat16 sA[128 * 32];
    __shared__ __hip_bfloat16 sB[128 * 32];

    const int tid = threadIdx.x;
    const int m0 = blockIdx.x * 128;
    const int n0 = blockIdx.y * 128;
    const int z  = blockIdx.z;
    const int ktBeg = z * KTILES_PER_SPLIT;

    // staging addresses: thread t loads 16B at (row = t/4, col8 = (t&3)*8)
    const int lrow = tid >> 2;
    const int lcol = (tid & 3) * 8;
    const __hip_bfloat16* ga = A + (size_t)(m0 + lrow) * KK + ktBeg * 32 + lcol;
    const __hip_bfloat16* gb = B + (size_t)(n0 + lrow) * KK + ktBeg * 32 + lcol;
    __hip_bfloat16* la = sA + tid * 8;   // row-major [128][32], contiguous in lane order
    __hip_bfloat16* lb = sB + tid * 8;

    // fragment addressing
    const int lane = tid & 63;
    const int quad = lane >> 4;
    const int l15  = lane & 15;
    const int mw   = (tid >> 6) & 1;     // wave m index (0..1)
    const int nw   = tid >> 7;           // wave n index (0..1)
    const int aBase = (mw * 64 + l15) * 32 + quad * 8;
    const int bBase = (nw * 64 + l15) * 32 + quad * 8;

    floatx4 acc[4][4];
#pragma unroll
    for (int i = 0; i < 4; ++i)
#pragma unroll
        for (int j = 0; j < 4; ++j) acc[i][j] = (floatx4)0.0f;

    for (int kt = 0; kt < KTILES_PER_SPLIT; ++kt) {
        gload_lds16(ga,            la);
        gload_lds16(ga + 64 * KK,  la + 2048);
        gload_lds16(gb,            lb);
        gload_lds16(gb + 64 * KK,  lb + 2048);
        ga += 32; gb += 32;
        __syncthreads();   // drains vmcnt (global_load_lds) + barrier

        short8 af[4], bfr[4];
#pragma unroll
        for (int i = 0; i < 4; ++i)
            af[i] = *(const short8*)(sA + aBase + i * 16 * 32);
#pragma unroll
        for (int j = 0; j < 4; ++j)
            bfr[j] = *(const short8*)(sB + bBase + j * 16 * 32);
#pragma unroll
        for (int i = 0; i < 4; ++i)
#pragma unroll
            for (int j = 0; j < 4; ++j)
                acc[i][j] = __builtin_amdgcn_mfma_f32_16x16x32_bf16(
                                af[i], bfr[j], acc[i][j], 0, 0, 0);
        __syncthreads();   // protect LDS before next stage
    }

    // epilogue: C/D layout col = lane&15, row = quad*4 + reg
    float* Pz = P + (size_t)z * BATCH * OUT;
#pragma unroll
    for (int i = 0; i < 4; ++i) {
        const int r0 = m0 + mw * 64 + i * 16 + quad * 4;
#pragma unroll
        for (int j = 0; j < 4; ++j) {
            const int c = n0 + nw * 64 + j * 16 + l15;
#pragma unroll
            for (int r = 0; r < 4; ++r)
                Pz[(size_t)(r0 + r) * OUT + c] = acc[i][j][r];
        }
    }
}

// ---------------------------------------------------------------------------
// Kernel 4: out = sum over SPLITK partials (float4 vectorized)
// ---------------------------------------------------------------------------
__global__ __launch_bounds__(256) void reducek(const floatx4* __restrict__ P,
                                               floatx4* __restrict__ out) {
    int j = blockIdx.x * 256 + threadIdx.x;        // [0, 4096*512/4)
    constexpr int STRIDE = BATCH * OUT / 4;        // 524288
    floatx4 s = P[j];
#pragma unroll
    for (int z = 1; z < SPLITK; ++z) s += P[(size_t)z * STRIDE + j];
    out[j] = s;
}

// ---------------------------------------------------------------------------
extern "C" void kernel_launch(void* const* d_in, const int* in_sizes, int n_in,
                              void* d_out, int out_size, void* d_ws, size_t ws_size,
                              hipStream_t stream) {
    const float* x     = (const float*)d_in[0];   // [4096,512]
    const float* w     = (const float*)d_in[1];   // [512,512]
    const float* coeff = (const float*)d_in[2];   // [512,512,9]
    float* out = (float*)d_out;                   // [4096,512]

    // workspace layout (bytes)
    char* ws = (char*)d_ws;
    __hip_bfloat16* J  = (__hip_bfloat16*)ws;                         // 37,748,736 B
    __hip_bfloat16* Cb = (__hip_bfloat16*)(ws + (size_t)BATCH * KK * 2);      // 4,718,592 B
    float* P = (float*)(ws + (size_t)BATCH * KK * 2 + (size_t)OUT * KK * 2);  // 33,554,432 B

    jprep<<<BATCH * IN / 256, 256, 0, stream>>>(x, J);
    cprep<<<OUT * IN / 256, 256, 0, stream>>>(w, coeff, Cb);
    gemm_splitk<<<dim3(BATCH / 128, OUT / 128, SPLITK), 256, 0, stream>>>(J, Cb, P);
    reducek<<<BATCH * OUT / 4 / 256, 256, 0, stream>>>((const floatx4*)P, (floatx4*)out);
}